// Round 1
// baseline (224.201 us; speedup 1.0000x reference)
//
#include <hip/hip_runtime.h>

#define NPG  256   // nodes per graph
#define EPG  4096  // edges per graph
#define FDIM 128
#define KTOP 30

// 512 threads/block = 8 waves = 2 waves/SIMD (was 1 — the kernel was
// latency-bound at 11% occupancy with VALUBusy 15%). Thread pair (t, t+256)
// shares node n = t&255: role A (half=0) owns channels 0..15, role B 16..31.
// Pairing across waves (not lane parity) keeps every W-row read wave-uniform
// -> scalar loads. LDS 55.3 KB < 64 KB static limit.
__global__ __launch_bounds__(512, 2)
void dgcnn_fused(const float* __restrict__ node_feat,
                 const int* __restrict__ srcv, const int* __restrict__ dstv,
                 const int* __restrict__ degs,
                 const float* __restrict__ W0, const float* __restrict__ b0,
                 const float* __restrict__ W1, const float* __restrict__ b1,
                 const float* __restrict__ W2, const float* __restrict__ b2,
                 const float* __restrict__ W3, const float* __restrict__ b3,
                 const float* __restrict__ cw1, const float* __restrict__ cb1,
                 const float* __restrict__ cw2, const float* __restrict__ cb2,
                 const float* __restrict__ ow,  const float* __restrict__ ob,
                 float* __restrict__ outp)
{
    __shared__ float Ybuf[NPG * 33];   // 33792 B; stride 33 -> bank (n+c)%32
    __shared__ int   srclist[EPG];     // 16384 B; in-edges grouped by dst; reused by tail
    __shared__ int   offs[NPG];
    __shared__ int   cnt [NPG];
    __shared__ int   degl[NPG];
    __shared__ float invd[NPG];
    __shared__ float keys[NPG];
    __shared__ int   wsum[4];
    // total ~55.3 KB

    const int g    = blockIdx.x;
    const int t    = threadIdx.x;
    const int n    = t & (NPG - 1);
    const int half = t >> 8;          // 0: channels 0..15, 1: channels 16..31
    const int co   = half * 16;

    // ================= degrees + wave-shuffle prefix scan (2 barriers) =======
    const int dn = degs[g * NPG + n];
    if (half == 0) {
        degl[n] = dn;
        cnt[n]  = 0;
        invd[n] = 1.0f / (float)(dn + 1);
    }
    {
        int v = (half == 0) ? dn : 0;
        const int lane = t & 63;
        #pragma unroll
        for (int off = 1; off < 64; off <<= 1) {
            int u = __shfl_up(v, off);
            if (lane >= off) v += u;
        }
        if (half == 0 && lane == 63) wsum[t >> 6] = v;   // wave totals (waves 0..3)
        __syncthreads();
        if (half == 0) {
            const int w = t >> 6;
            int base = 0;
            #pragma unroll
            for (int i = 0; i < 4; i++) base += (i < w) ? wsum[i] : 0;
            offs[n] = base + v - dn;   // exclusive prefix of in-degrees
        }
        __syncthreads();
    }

    // ================= edge-list build (counting sort by dst) ================
    {
        const int* sg = srcv + g * EPG;
        const int* dg = dstv + g * EPG;
        #pragma unroll
        for (int i = 0; i < EPG / 512; i++) {
            int e  = t + i * 512;
            int ss = sg[e] & (NPG - 1);   // graphs are 256-node aligned
            int dd = dg[e] & (NPG - 1);
            int p  = atomicAdd(&cnt[dd], 1);
            srclist[offs[dd] + p] = ss;
        }
    }

    // ================= phase 0: y0 = node_feat @ W0 ==========================
    // Each thread loads 64 floats (its k-half of node n's row) to registers:
    // no LDS staging, no chunk barriers. Pair lanes touch disjoint halves of
    // the same 512B row -> lines fully consumed, HBM traffic unchanged.
    {
        const float* nf = node_feat + ((size_t)g * NPG + n) * FDIM + half * 64;
        float4 rv[16];
        #pragma unroll
        for (int i = 0; i < 16; i++) rv[i] = ((const float4*)nf)[i];

        float acc[32];
        #pragma unroll
        for (int c = 0; c < 32; c++) acc[c] = 0.f;
        #pragma unroll
        for (int kk = 0; kk < 16; kk++) {
            const float hx[4] = {rv[kk].x, rv[kk].y, rv[kk].z, rv[kk].w};
            #pragma unroll
            for (int q = 0; q < 4; q++) {
                const float* wr = W0 + (half * 64 + kk * 4 + q) * 32; // wave-uniform
                const float  hk = hx[q];
                #pragma unroll
                for (int c = 0; c < 32; c++) acc[c] = fmaf(hk, wr[c], acc[c]);
            }
        }
        __syncthreads();   // edge build complete; Ybuf first use
        if (half == 0) {
            #pragma unroll
            for (int c = 0; c < 32; c++) Ybuf[n * 33 + c] = acc[c];
        }
        __syncthreads();
        if (half == 1) {
            #pragma unroll
            for (int c = 0; c < 32; c++) Ybuf[n * 33 + c] += acc[c];
        }
        __syncthreads();
    }

    const float iv = invd[n];
    const int   o  = offs[n];
    const int   d  = degl[n];

    // pooled (my 16-channel half) = y[n] + sum_{in-edges} y[src]
    auto agg16 = [&](float (&h)[16]) {
        const float* self = &Ybuf[n * 33 + co];
        #pragma unroll
        for (int c = 0; c < 16; c++) h[c] = self[c];
        for (int j = 0; j < d; j++) {
            const float* yr = &Ybuf[srclist[o + j] * 33 + co];
            #pragma unroll
            for (int c = 0; c < 16; c++) h[c] += yr[c];
        }
    };
    auto act16 = [&](float (&h)[16], const float* bb) {
        #pragma unroll
        for (int c = 0; c < 16; c++) h[c] = tanhf((h[c] + bb[co + c]) * iv);
    };
    // y_next = h @ Wn, k-split across the pair; combine via 2 barriered passes
    auto matml16 = [&](const float (&h)[16], const float* Wn) {
        float a[32];
        #pragma unroll
        for (int c = 0; c < 32; c++) a[c] = 0.f;
        #pragma unroll
        for (int kk = 0; kk < 16; kk++) {
            const float* wr = Wn + (co + kk) * 32;   // wave-uniform -> scalar loads
            const float  hk = h[kk];
            #pragma unroll
            for (int c = 0; c < 32; c++) a[c] = fmaf(hk, wr[c], a[c]);
        }
        __syncthreads();   // all agg reads of old Ybuf complete
        if (half == 0) {
            #pragma unroll
            for (int c = 0; c < 32; c++) Ybuf[n * 33 + c] = a[c];
        }
        __syncthreads();
        if (half == 1) {
            #pragma unroll
            for (int c = 0; c < 32; c++) Ybuf[n * 33 + c] += a[c];
        }
        __syncthreads();
    };

    // ================= 4 GNN layers =================
    float h1[16], h2[16], h3[16];
    agg16(h1); act16(h1, b0); matml16(h1, W1);
    agg16(h2); act16(h2, b1); matml16(h2, W2);
    agg16(h3); act16(h3, b2);
    {   // layer 3 projection: y3 = h3 @ W3 (32x1), k-split + combine
        float a3 = 0.f;
        #pragma unroll
        for (int kk = 0; kk < 16; kk++) a3 = fmaf(h3[kk], W3[co + kk], a3);
        __syncthreads();   // all layer-2 agg reads complete
        if (half == 0) Ybuf[n * 33] = a3;
        __syncthreads();
        if (half == 1) Ybuf[n * 33] += a3;
        __syncthreads();
    }
    float kv;
    {   // layer 3 aggregate (1-wide) + activation -> sort key (both halves redundant)
        float s = Ybuf[n * 33];
        for (int j = 0; j < d; j++) s += Ybuf[srclist[o + j] * 33];
        kv = tanhf((s + b3[0]) * iv);
        if (half == 0) keys[n] = kv;
    }
    __syncthreads();

    // ================= sortpool: rank-based top-K (jax tie-break: lower idx) ==
    int rank = 0;
    #pragma unroll 4
    for (int j = 0; j < NPG; j++) {
        float vj = keys[j];
        rank += ((vj > kv) || ((vj == kv) && (j < n))) ? 1 : 0;
    }

    // ================= export selected Z rows, then conv tail ================
    float* sp    = (float*)srclist;   // 2910 floats (srclist dead from here)
    float* x1    = sp + 30 * 97;      // 480
    float* xp    = x1 + 480;          // 240
    float* dense = xp + 240;          // 352  (total 3982 floats <= 4096)

    if (rank < KTOP) {
        float* dp = sp + rank * 97 + co;
        #pragma unroll
        for (int c = 0; c < 16; c++) dp[c]      = h1[c];
        #pragma unroll
        for (int c = 0; c < 16; c++) dp[32 + c] = h2[c];
        #pragma unroll
        for (int c = 0; c < 16; c++) dp[64 + c] = h3[c];
        if (half == 0) sp[rank * 97 + 96] = kv;
    }
    __syncthreads();

    // conv1: kernel width 97, stride 97 -> per-row dot; out [16][30], relu
    for (int idx = t; idx < 480; idx += 512) {
        int k = idx >> 4, c = idx & 15;
        float s = cb1[c];
        for (int dd = 0; dd < 97; dd++) s = fmaf(sp[k * 97 + dd], cw1[c * 97 + dd], s);
        x1[c * 30 + k] = fmaxf(s, 0.f);
    }
    __syncthreads();
    // maxpool1d(2,2) -> [16][15]
    for (int idx = t; idx < 240; idx += 512) {
        int c = idx / 15, k = idx - c * 15;
        xp[idx] = fmaxf(x1[c * 30 + 2 * k], x1[c * 30 + 2 * k + 1]);
    }
    __syncthreads();
    // conv2: [32][16][5] VALID over 15 -> [32][11], relu; dense idx = c*11+j
    for (int idx = t; idx < 352; idx += 512) {
        int c = idx / 11, j = idx - c * 11;
        float s = cb2[c];
        for (int i2 = 0; i2 < 16; i2++) {
            #pragma unroll
            for (int tt = 0; tt < 5; tt++)
                s = fmaf(xp[i2 * 15 + j + tt], cw2[(c * 16 + i2) * 5 + tt], s);
        }
        dense[idx] = fmaxf(s, 0.f);
    }
    __syncthreads();
    // output: relu(relu(dense @ out_w + out_b)) -> [2]
    if (t < 64) {
        float a0 = 0.f, a1 = 0.f;
        for (int dd = t; dd < 352; dd += 64) {
            float v = dense[dd];
            a0 = fmaf(v, ow[dd * 2],     a0);
            a1 = fmaf(v, ow[dd * 2 + 1], a1);
        }
        #pragma unroll
        for (int off2 = 32; off2 > 0; off2 >>= 1) {
            a0 += __shfl_down(a0, off2);
            a1 += __shfl_down(a1, off2);
        }
        if (t == 0) {
            outp[g * 2 + 0] = fmaxf(a0 + ob[0], 0.f);
            outp[g * 2 + 1] = fmaxf(a1 + ob[1], 0.f);
        }
    }
}

extern "C" void kernel_launch(void* const* d_in, const int* in_sizes, int n_in,
                              void* d_out, int out_size, void* d_ws, size_t ws_size,
                              hipStream_t stream) {
    const float* node_feat = (const float*)d_in[0];
    const int*   src       = (const int*)  d_in[1];
    const int*   dst       = (const int*)  d_in[2];
    const int*   degsp     = (const int*)  d_in[3];
    const float* W0 = (const float*)d_in[4];
    const float* b0 = (const float*)d_in[5];
    const float* W1 = (const float*)d_in[6];
    const float* b1 = (const float*)d_in[7];
    const float* W2 = (const float*)d_in[8];
    const float* b2 = (const float*)d_in[9];
    const float* W3 = (const float*)d_in[10];
    const float* b3 = (const float*)d_in[11];
    const float* cw1 = (const float*)d_in[12];
    const float* cb1 = (const float*)d_in[13];
    const float* cw2 = (const float*)d_in[14];
    const float* cb2 = (const float*)d_in[15];
    const float* ow  = (const float*)d_in[16];
    const float* ob  = (const float*)d_in[17];

    dgcnn_fused<<<dim3(256), dim3(512), 0, stream>>>(
        node_feat, src, dst, degsp,
        W0, b0, W1, b1, W2, b2, W3, b3,
        cw1, cb1, cw2, cb2, ow, ob, (float*)d_out);
}

// Round 2
// 220.949 us; speedup vs baseline: 1.0147x; 1.0147x over previous
//
#include <hip/hip_runtime.h>

#define NPG  256   // nodes per graph
#define EPG  4096  // edges per graph
#define FDIM 128
#define KTOP 30

// 512 threads/block = 8 waves = 2 waves/SIMD. Thread pair (t, t+256) shares
// node n = t&255: role A (half=0) owns channels 0..15, role B 16..31.
// Pairing across waves keeps every W-row read wave-uniform -> scalar loads.
// Round-1 lesson: __launch_bounds__(512,2) caps VGPR at 128; phase 0 must not
// hold the whole 64-float row in registers (it spilled 60 MB of scratch).
// Phase 0 now uses a 2-deep 16-float pipeline: peak live ~80 VGPR, no spill.
__global__ __launch_bounds__(512, 2)
void dgcnn_fused(const float* __restrict__ node_feat,
                 const int* __restrict__ srcv, const int* __restrict__ dstv,
                 const int* __restrict__ degs,
                 const float* __restrict__ W0, const float* __restrict__ b0,
                 const float* __restrict__ W1, const float* __restrict__ b1,
                 const float* __restrict__ W2, const float* __restrict__ b2,
                 const float* __restrict__ W3, const float* __restrict__ b3,
                 const float* __restrict__ cw1, const float* __restrict__ cb1,
                 const float* __restrict__ cw2, const float* __restrict__ cb2,
                 const float* __restrict__ ow,  const float* __restrict__ ob,
                 float* __restrict__ outp)
{
    __shared__ float Ybuf[NPG * 33];   // 33792 B; stride 33 -> bank (n+c)%32
    __shared__ int   srclist[EPG];     // 16384 B; in-edges grouped by dst; reused by tail
    __shared__ int   offs[NPG];
    __shared__ int   cnt [NPG];
    __shared__ int   degl[NPG];
    __shared__ float invd[NPG];
    __shared__ float keys[NPG];
    __shared__ int   wsum[4];
    // total ~55.3 KB

    const int g    = blockIdx.x;
    const int t    = threadIdx.x;
    const int n    = t & (NPG - 1);
    const int half = t >> 8;          // 0: channels 0..15, 1: channels 16..31
    const int co   = half * 16;

    // ================= degrees + wave-shuffle prefix scan (2 barriers) =======
    const int dn = degs[g * NPG + n];
    if (half == 0) {
        degl[n] = dn;
        cnt[n]  = 0;
        invd[n] = 1.0f / (float)(dn + 1);
    }
    {
        int v = (half == 0) ? dn : 0;
        const int lane = t & 63;
        #pragma unroll
        for (int off = 1; off < 64; off <<= 1) {
            int u = __shfl_up(v, off);
            if (lane >= off) v += u;
        }
        if (half == 0 && lane == 63) wsum[t >> 6] = v;   // wave totals (waves 0..3)
        __syncthreads();
        if (half == 0) {
            const int w = t >> 6;
            int base = 0;
            #pragma unroll
            for (int i = 0; i < 4; i++) base += (i < w) ? wsum[i] : 0;
            offs[n] = base + v - dn;   // exclusive prefix of in-degrees
        }
        __syncthreads();
    }

    // ================= edge-list build (counting sort by dst) ================
    {
        const int* sg = srcv + g * EPG;
        const int* dg = dstv + g * EPG;
        #pragma unroll
        for (int i = 0; i < EPG / 512; i++) {
            int e  = t + i * 512;
            int ss = sg[e] & (NPG - 1);   // graphs are 256-node aligned
            int dd = dg[e] & (NPG - 1);
            int p  = atomicAdd(&cnt[dd], 1);
            srclist[offs[dd] + p] = ss;
        }
    }

    // ================= phase 0: y0 = node_feat @ W0 ==========================
    // k-split: this thread covers k in [half*64, half*64+64). Stream the row in
    // 16-float batches through two named buffers (2-deep pipeline): loads for
    // batch i+1 are in flight while batch i feeds the FMAs. Peak live set:
    // acc[32] + ra[16] + rb[16] ~ 80 VGPR -> no spill under the 128 cap.
    {
        const float* nf = node_feat + ((size_t)g * NPG + n) * FDIM + half * 64;
        float acc[32];
        #pragma unroll
        for (int c = 0; c < 32; c++) acc[c] = 0.f;

        auto fma16 = [&](const float4 (&r)[4], int kbase) {
            const float hx[16] = {r[0].x, r[0].y, r[0].z, r[0].w,
                                  r[1].x, r[1].y, r[1].z, r[1].w,
                                  r[2].x, r[2].y, r[2].z, r[2].w,
                                  r[3].x, r[3].y, r[3].z, r[3].w};
            #pragma unroll
            for (int q = 0; q < 16; q++) {
                const float* wr = W0 + (kbase + q) * 32;   // wave-uniform -> scalar
                #pragma unroll
                for (int c = 0; c < 32; c++) acc[c] = fmaf(hx[q], wr[c], acc[c]);
            }
        };

        float4 ra[4], rb[4];
        #pragma unroll
        for (int i = 0; i < 4; i++) ra[i] = ((const float4*)nf)[i];
        #pragma unroll
        for (int i = 0; i < 4; i++) rb[i] = ((const float4*)nf)[4 + i];
        fma16(ra, half * 64 + 0);
        #pragma unroll
        for (int i = 0; i < 4; i++) ra[i] = ((const float4*)nf)[8 + i];
        fma16(rb, half * 64 + 16);
        #pragma unroll
        for (int i = 0; i < 4; i++) rb[i] = ((const float4*)nf)[12 + i];
        fma16(ra, half * 64 + 32);
        fma16(rb, half * 64 + 48);

        __syncthreads();   // edge build complete; Ybuf first use
        if (half == 0) {
            #pragma unroll
            for (int c = 0; c < 32; c++) Ybuf[n * 33 + c] = acc[c];
        }
        __syncthreads();
        if (half == 1) {
            #pragma unroll
            for (int c = 0; c < 32; c++) Ybuf[n * 33 + c] += acc[c];
        }
        __syncthreads();
    }

    const float iv = invd[n];
    const int   o  = offs[n];
    const int   d  = degl[n];

    // pooled (my 16-channel half) = y[n] + sum_{in-edges} y[src]
    auto agg16 = [&](float (&h)[16]) {
        const float* self = &Ybuf[n * 33 + co];
        #pragma unroll
        for (int c = 0; c < 16; c++) h[c] = self[c];
        for (int j = 0; j < d; j++) {
            const float* yr = &Ybuf[srclist[o + j] * 33 + co];
            #pragma unroll
            for (int c = 0; c < 16; c++) h[c] += yr[c];
        }
    };
    auto act16 = [&](float (&h)[16], const float* bb) {
        #pragma unroll
        for (int c = 0; c < 16; c++) h[c] = tanhf((h[c] + bb[co + c]) * iv);
    };
    // y_next = h @ Wn, k-split across the pair; combine via 2 barriered passes
    auto matml16 = [&](const float (&h)[16], const float* Wn) {
        float a[32];
        #pragma unroll
        for (int c = 0; c < 32; c++) a[c] = 0.f;
        #pragma unroll
        for (int kk = 0; kk < 16; kk++) {
            const float* wr = Wn + (co + kk) * 32;   // wave-uniform -> scalar loads
            const float  hk = h[kk];
            #pragma unroll
            for (int c = 0; c < 32; c++) a[c] = fmaf(hk, wr[c], a[c]);
        }
        __syncthreads();   // all agg reads of old Ybuf complete
        if (half == 0) {
            #pragma unroll
            for (int c = 0; c < 32; c++) Ybuf[n * 33 + c] = a[c];
        }
        __syncthreads();
        if (half == 1) {
            #pragma unroll
            for (int c = 0; c < 32; c++) Ybuf[n * 33 + c] += a[c];
        }
        __syncthreads();
    };

    // ================= 4 GNN layers =================
    float h1[16], h2[16], h3[16];
    agg16(h1); act16(h1, b0); matml16(h1, W1);
    agg16(h2); act16(h2, b1); matml16(h2, W2);
    agg16(h3); act16(h3, b2);
    {   // layer 3 projection: y3 = h3 @ W3 (32x1), k-split + combine
        float a3 = 0.f;
        #pragma unroll
        for (int kk = 0; kk < 16; kk++) a3 = fmaf(h3[kk], W3[co + kk], a3);
        __syncthreads();   // all layer-2 agg reads complete
        if (half == 0) Ybuf[n * 33] = a3;
        __syncthreads();
        if (half == 1) Ybuf[n * 33] += a3;
        __syncthreads();
    }
    float kv;
    {   // layer 3 aggregate (1-wide) + activation -> sort key (both halves redundant)
        float s = Ybuf[n * 33];
        for (int j = 0; j < d; j++) s += Ybuf[srclist[o + j] * 33];
        kv = tanhf((s + b3[0]) * iv);
        if (half == 0) keys[n] = kv;
    }
    __syncthreads();

    // ================= sortpool: rank-based top-K (jax tie-break: lower idx) ==
    int rank = 0;
    #pragma unroll 4
    for (int j = 0; j < NPG; j++) {
        float vj = keys[j];
        rank += ((vj > kv) || ((vj == kv) && (j < n))) ? 1 : 0;
    }

    // ================= export selected Z rows, then conv tail ================
    float* sp    = (float*)srclist;   // 2910 floats (srclist dead from here)
    float* x1    = sp + 30 * 97;      // 480
    float* xp    = x1 + 480;          // 240
    float* dense = xp + 240;          // 352  (total 3982 floats <= 4096)

    if (rank < KTOP) {
        float* dp = sp + rank * 97 + co;
        #pragma unroll
        for (int c = 0; c < 16; c++) dp[c]      = h1[c];
        #pragma unroll
        for (int c = 0; c < 16; c++) dp[32 + c] = h2[c];
        #pragma unroll
        for (int c = 0; c < 16; c++) dp[64 + c] = h3[c];
        if (half == 0) sp[rank * 97 + 96] = kv;
    }
    __syncthreads();

    // conv1: kernel width 97, stride 97 -> per-row dot; out [16][30], relu
    for (int idx = t; idx < 480; idx += 512) {
        int k = idx >> 4, c = idx & 15;
        float s = cb1[c];
        for (int dd = 0; dd < 97; dd++) s = fmaf(sp[k * 97 + dd], cw1[c * 97 + dd], s);
        x1[c * 30 + k] = fmaxf(s, 0.f);
    }
    __syncthreads();
    // maxpool1d(2,2) -> [16][15]
    for (int idx = t; idx < 240; idx += 512) {
        int c = idx / 15, k = idx - c * 15;
        xp[idx] = fmaxf(x1[c * 30 + 2 * k], x1[c * 30 + 2 * k + 1]);
    }
    __syncthreads();
    // conv2: [32][16][5] VALID over 15 -> [32][11], relu; dense idx = c*11+j
    for (int idx = t; idx < 352; idx += 512) {
        int c = idx / 11, j = idx - c * 11;
        float s = cb2[c];
        for (int i2 = 0; i2 < 16; i2++) {
            #pragma unroll
            for (int tt = 0; tt < 5; tt++)
                s = fmaf(xp[i2 * 15 + j + tt], cw2[(c * 16 + i2) * 5 + tt], s);
        }
        dense[idx] = fmaxf(s, 0.f);
    }
    __syncthreads();
    // output: relu(relu(dense @ out_w + out_b)) -> [2]
    if (t < 64) {
        float a0 = 0.f, a1 = 0.f;
        for (int dd = t; dd < 352; dd += 64) {
            float v = dense[dd];
            a0 = fmaf(v, ow[dd * 2],     a0);
            a1 = fmaf(v, ow[dd * 2 + 1], a1);
        }
        #pragma unroll
        for (int off2 = 32; off2 > 0; off2 >>= 1) {
            a0 += __shfl_down(a0, off2);
            a1 += __shfl_down(a1, off2);
        }
        if (t == 0) {
            outp[g * 2 + 0] = fmaxf(a0 + ob[0], 0.f);
            outp[g * 2 + 1] = fmaxf(a1 + ob[1], 0.f);
        }
    }
}

extern "C" void kernel_launch(void* const* d_in, const int* in_sizes, int n_in,
                              void* d_out, int out_size, void* d_ws, size_t ws_size,
                              hipStream_t stream) {
    const float* node_feat = (const float*)d_in[0];
    const int*   src       = (const int*)  d_in[1];
    const int*   dst       = (const int*)  d_in[2];
    const int*   degsp     = (const int*)  d_in[3];
    const float* W0 = (const float*)d_in[4];
    const float* b0 = (const float*)d_in[5];
    const float* W1 = (const float*)d_in[6];
    const float* b1 = (const float*)d_in[7];
    const float* W2 = (const float*)d_in[8];
    const float* b2 = (const float*)d_in[9];
    const float* W3 = (const float*)d_in[10];
    const float* b3 = (const float*)d_in[11];
    const float* cw1 = (const float*)d_in[12];
    const float* cb1 = (const float*)d_in[13];
    const float* cw2 = (const float*)d_in[14];
    const float* cb2 = (const float*)d_in[15];
    const float* ow  = (const float*)d_in[16];
    const float* ob  = (const float*)d_in[17];

    dgcnn_fused<<<dim3(256), dim3(512), 0, stream>>>(
        node_feat, src, dst, degsp,
        W0, b0, W1, b1, W2, b2, W3, b3,
        cw1, cb1, cw2, cb2, ow, ob, (float*)d_out);
}

// Round 3
// 220.749 us; speedup vs baseline: 1.0156x; 1.0009x over previous
//
#include <hip/hip_runtime.h>

#define NPG  256   // nodes per graph
#define EPG  4096  // edges per graph
#define FDIM 128
#define KTOP 30

// 512 threads/block = 8 waves = 2 waves/SIMD. Thread pair (t, t+256) shares
// node n = t&255: role A (half=0) owns channels 0..15, role B 16..31.
// Pairing across waves keeps every W-row read wave-uniform -> scalar loads.
//
// Round-1/2 lesson: __launch_bounds__(512,2) acts as 2 BLOCKS/CU (CUDA
// semantics) -> 16 waves/CU -> VGPR capped at 128 -> ~100 MB/dispatch of
// scratch spill traffic (WRITE_SIZE 49-60 MB, VGPR_Count pinned at 128).
// The grid is 1 block/CU anyway, so the cap bought nothing. (512,1) lifts
// the cap to 256 VGPR; the ~100-140 live set allocates with zero spill.
__global__ __launch_bounds__(512, 1)
void dgcnn_fused(const float* __restrict__ node_feat,
                 const int* __restrict__ srcv, const int* __restrict__ dstv,
                 const int* __restrict__ degs,
                 const float* __restrict__ W0, const float* __restrict__ b0,
                 const float* __restrict__ W1, const float* __restrict__ b1,
                 const float* __restrict__ W2, const float* __restrict__ b2,
                 const float* __restrict__ W3, const float* __restrict__ b3,
                 const float* __restrict__ cw1, const float* __restrict__ cb1,
                 const float* __restrict__ cw2, const float* __restrict__ cb2,
                 const float* __restrict__ ow,  const float* __restrict__ ob,
                 float* __restrict__ outp)
{
    __shared__ float Ybuf[NPG * 33];   // 33792 B; stride 33 -> bank (n+c)%32
    __shared__ int   srclist[EPG];     // 16384 B; in-edges grouped by dst; reused by tail
    __shared__ int   offs[NPG];
    __shared__ int   cnt [NPG];
    __shared__ int   degl[NPG];
    __shared__ float invd[NPG];
    __shared__ float keys[NPG];
    __shared__ int   wsum[4];
    // total ~55.3 KB

    const int g    = blockIdx.x;
    const int t    = threadIdx.x;
    const int n    = t & (NPG - 1);
    const int half = t >> 8;          // 0: channels 0..15, 1: channels 16..31
    const int co   = half * 16;

    // ================= degrees + wave-shuffle prefix scan (2 barriers) =======
    const int dn = degs[g * NPG + n];
    if (half == 0) {
        degl[n] = dn;
        cnt[n]  = 0;
        invd[n] = 1.0f / (float)(dn + 1);
    }
    {
        int v = (half == 0) ? dn : 0;
        const int lane = t & 63;
        #pragma unroll
        for (int off = 1; off < 64; off <<= 1) {
            int u = __shfl_up(v, off);
            if (lane >= off) v += u;
        }
        if (half == 0 && lane == 63) wsum[t >> 6] = v;   // wave totals (waves 0..3)
        __syncthreads();
        if (half == 0) {
            const int w = t >> 6;
            int base = 0;
            #pragma unroll
            for (int i = 0; i < 4; i++) base += (i < w) ? wsum[i] : 0;
            offs[n] = base + v - dn;   // exclusive prefix of in-degrees
        }
        __syncthreads();
    }

    // ================= edge-list build (counting sort by dst) ================
    {
        const int* sg = srcv + g * EPG;
        const int* dg = dstv + g * EPG;
        #pragma unroll
        for (int i = 0; i < EPG / 512; i++) {
            int e  = t + i * 512;
            int ss = sg[e] & (NPG - 1);   // graphs are 256-node aligned
            int dd = dg[e] & (NPG - 1);
            int p  = atomicAdd(&cnt[dd], 1);
            srclist[offs[dd] + p] = ss;
        }
    }

    // ================= phase 0: y0 = node_feat @ W0 ==========================
    // k-split: this thread covers k in [half*64, half*64+64). Stream the row in
    // 16-float batches through two named buffers (2-deep pipeline).
    {
        const float* nf = node_feat + ((size_t)g * NPG + n) * FDIM + half * 64;
        float acc[32];
        #pragma unroll
        for (int c = 0; c < 32; c++) acc[c] = 0.f;

        auto fma16 = [&](const float4 (&r)[4], int kbase) {
            const float hx[16] = {r[0].x, r[0].y, r[0].z, r[0].w,
                                  r[1].x, r[1].y, r[1].z, r[1].w,
                                  r[2].x, r[2].y, r[2].z, r[2].w,
                                  r[3].x, r[3].y, r[3].z, r[3].w};
            #pragma unroll
            for (int q = 0; q < 16; q++) {
                const float* wr = W0 + (kbase + q) * 32;   // wave-uniform -> scalar
                #pragma unroll
                for (int c = 0; c < 32; c++) acc[c] = fmaf(hx[q], wr[c], acc[c]);
            }
        };

        float4 ra[4], rb[4];
        #pragma unroll
        for (int i = 0; i < 4; i++) ra[i] = ((const float4*)nf)[i];
        #pragma unroll
        for (int i = 0; i < 4; i++) rb[i] = ((const float4*)nf)[4 + i];
        fma16(ra, half * 64 + 0);
        #pragma unroll
        for (int i = 0; i < 4; i++) ra[i] = ((const float4*)nf)[8 + i];
        fma16(rb, half * 64 + 16);
        #pragma unroll
        for (int i = 0; i < 4; i++) rb[i] = ((const float4*)nf)[12 + i];
        fma16(ra, half * 64 + 32);
        fma16(rb, half * 64 + 48);

        __syncthreads();   // edge build complete; Ybuf first use
        if (half == 0) {
            #pragma unroll
            for (int c = 0; c < 32; c++) Ybuf[n * 33 + c] = acc[c];
        }
        __syncthreads();
        if (half == 1) {
            #pragma unroll
            for (int c = 0; c < 32; c++) Ybuf[n * 33 + c] += acc[c];
        }
        __syncthreads();
    }

    const float iv = invd[n];
    const int   o  = offs[n];
    const int   d  = degl[n];

    // pooled (my 16-channel half) = y[n] + sum_{in-edges} y[src]
    auto agg16 = [&](float (&h)[16]) {
        const float* self = &Ybuf[n * 33 + co];
        #pragma unroll
        for (int c = 0; c < 16; c++) h[c] = self[c];
        for (int j = 0; j < d; j++) {
            const float* yr = &Ybuf[srclist[o + j] * 33 + co];
            #pragma unroll
            for (int c = 0; c < 16; c++) h[c] += yr[c];
        }
    };
    auto act16 = [&](float (&h)[16], const float* bb) {
        #pragma unroll
        for (int c = 0; c < 16; c++) h[c] = tanhf((h[c] + bb[co + c]) * iv);
    };
    // y_next = h @ Wn, k-split across the pair; combine via 2 barriered passes
    auto matml16 = [&](const float (&h)[16], const float* Wn) {
        float a[32];
        #pragma unroll
        for (int c = 0; c < 32; c++) a[c] = 0.f;
        #pragma unroll
        for (int kk = 0; kk < 16; kk++) {
            const float* wr = Wn + (co + kk) * 32;   // wave-uniform -> scalar loads
            const float  hk = h[kk];
            #pragma unroll
            for (int c = 0; c < 32; c++) a[c] = fmaf(hk, wr[c], a[c]);
        }
        __syncthreads();   // all agg reads of old Ybuf complete
        if (half == 0) {
            #pragma unroll
            for (int c = 0; c < 32; c++) Ybuf[n * 33 + c] = a[c];
        }
        __syncthreads();
        if (half == 1) {
            #pragma unroll
            for (int c = 0; c < 32; c++) Ybuf[n * 33 + c] += a[c];
        }
        __syncthreads();
    };

    // ================= 4 GNN layers =================
    float h1[16], h2[16], h3[16];
    agg16(h1); act16(h1, b0); matml16(h1, W1);
    agg16(h2); act16(h2, b1); matml16(h2, W2);
    agg16(h3); act16(h3, b2);
    {   // layer 3 projection: y3 = h3 @ W3 (32x1), k-split + combine
        float a3 = 0.f;
        #pragma unroll
        for (int kk = 0; kk < 16; kk++) a3 = fmaf(h3[kk], W3[co + kk], a3);
        __syncthreads();   // all layer-2 agg reads complete
        if (half == 0) Ybuf[n * 33] = a3;
        __syncthreads();
        if (half == 1) Ybuf[n * 33] += a3;
        __syncthreads();
    }
    float kv;
    {   // layer 3 aggregate (1-wide) + activation -> sort key (both halves redundant)
        float s = Ybuf[n * 33];
        for (int j = 0; j < d; j++) s += Ybuf[srclist[o + j] * 33];
        kv = tanhf((s + b3[0]) * iv);
        if (half == 0) keys[n] = kv;
    }
    __syncthreads();

    // ================= sortpool: rank-based top-K (jax tie-break: lower idx) ==
    int rank = 0;
    #pragma unroll 4
    for (int j = 0; j < NPG; j++) {
        float vj = keys[j];
        rank += ((vj > kv) || ((vj == kv) && (j < n))) ? 1 : 0;
    }

    // ================= export selected Z rows, then conv tail ================
    float* sp    = (float*)srclist;   // 2910 floats (srclist dead from here)
    float* x1    = sp + 30 * 97;      // 480
    float* xp    = x1 + 480;          // 240
    float* dense = xp + 240;          // 352  (total 3982 floats <= 4096)

    if (rank < KTOP) {
        float* dp = sp + rank * 97 + co;
        #pragma unroll
        for (int c = 0; c < 16; c++) dp[c]      = h1[c];
        #pragma unroll
        for (int c = 0; c < 16; c++) dp[32 + c] = h2[c];
        #pragma unroll
        for (int c = 0; c < 16; c++) dp[64 + c] = h3[c];
        if (half == 0) sp[rank * 97 + 96] = kv;
    }
    __syncthreads();

    // conv1: kernel width 97, stride 97 -> per-row dot; out [16][30], relu
    for (int idx = t; idx < 480; idx += 512) {
        int k = idx >> 4, c = idx & 15;
        float s = cb1[c];
        for (int dd = 0; dd < 97; dd++) s = fmaf(sp[k * 97 + dd], cw1[c * 97 + dd], s);
        x1[c * 30 + k] = fmaxf(s, 0.f);
    }
    __syncthreads();
    // maxpool1d(2,2) -> [16][15]
    for (int idx = t; idx < 240; idx += 512) {
        int c = idx / 15, k = idx - c * 15;
        xp[idx] = fmaxf(x1[c * 30 + 2 * k], x1[c * 30 + 2 * k + 1]);
    }
    __syncthreads();
    // conv2: [32][16][5] VALID over 15 -> [32][11], relu; dense idx = c*11+j
    for (int idx = t; idx < 352; idx += 512) {
        int c = idx / 11, j = idx - c * 11;
        float s = cb2[c];
        for (int i2 = 0; i2 < 16; i2++) {
            #pragma unroll
            for (int tt = 0; tt < 5; tt++)
                s = fmaf(xp[i2 * 15 + j + tt], cw2[(c * 16 + i2) * 5 + tt], s);
        }
        dense[idx] = fmaxf(s, 0.f);
    }
    __syncthreads();
    // output: relu(relu(dense @ out_w + out_b)) -> [2]
    if (t < 64) {
        float a0 = 0.f, a1 = 0.f;
        for (int dd = t; dd < 352; dd += 64) {
            float v = dense[dd];
            a0 = fmaf(v, ow[dd * 2],     a0);
            a1 = fmaf(v, ow[dd * 2 + 1], a1);
        }
        #pragma unroll
        for (int off2 = 32; off2 > 0; off2 >>= 1) {
            a0 += __shfl_down(a0, off2);
            a1 += __shfl_down(a1, off2);
        }
        if (t == 0) {
            outp[g * 2 + 0] = fmaxf(a0 + ob[0], 0.f);
            outp[g * 2 + 1] = fmaxf(a1 + ob[1], 0.f);
        }
    }
}

extern "C" void kernel_launch(void* const* d_in, const int* in_sizes, int n_in,
                              void* d_out, int out_size, void* d_ws, size_t ws_size,
                              hipStream_t stream) {
    const float* node_feat = (const float*)d_in[0];
    const int*   src       = (const int*)  d_in[1];
    const int*   dst       = (const int*)  d_in[2];
    const int*   degsp     = (const int*)  d_in[3];
    const float* W0 = (const float*)d_in[4];
    const float* b0 = (const float*)d_in[5];
    const float* W1 = (const float*)d_in[6];
    const float* b1 = (const float*)d_in[7];
    const float* W2 = (const float*)d_in[8];
    const float* b2 = (const float*)d_in[9];
    const float* W3 = (const float*)d_in[10];
    const float* b3 = (const float*)d_in[11];
    const float* cw1 = (const float*)d_in[12];
    const float* cb1 = (const float*)d_in[13];
    const float* cw2 = (const float*)d_in[14];
    const float* cb2 = (const float*)d_in[15];
    const float* ow  = (const float*)d_in[16];
    const float* ob  = (const float*)d_in[17];

    dgcnn_fused<<<dim3(256), dim3(512), 0, stream>>>(
        node_feat, src, dst, degsp,
        W0, b0, W1, b1, W2, b2, W3, b3,
        cw1, cb1, cw2, cb2, ow, ob, (float*)d_out);
}

// Round 4
// 205.532 us; speedup vs baseline: 1.0908x; 1.0740x over previous
//
#include <hip/hip_runtime.h>

#define NPG  256   // nodes per graph
#define EPG  4096  // edges per graph
#define FDIM 128
#define KTOP 30

// 512 threads/block = 8 waves = 2 waves/SIMD. Thread pair (t, t+256) shares
// node n = t&255: role A (half=0) owns channels 0..15, role B 16..31.
// Pairing across waves keeps every W-row read wave-uniform -> scalar loads.
//
// Rounds 1-3 lesson: with LDS=55.8KB, TWO 512-thread blocks fit per CU, so
// the backend's occupancy heuristic targets 4 waves/EU and pins the VGPR
// budget at 512/4 = 128 (observed VGPR_Count==128 in all three rounds,
// regardless of __launch_bounds__ 2nd arg), spilling ~375 B/thread -> 49 MB
// scratch writes + 47 MB re-reads per dispatch = the entire runtime.
// The grid is 1 block/CU, so that co-residency goal is pure loss.
// amdgpu_waves_per_eu(2,2) pins the target at 2 waves/EU -> 256-VGPR budget
// -> the ~100-VGPR live set allocates with zero spill.
__global__ __launch_bounds__(512)
__attribute__((amdgpu_waves_per_eu(2, 2)))
void dgcnn_fused(const float* __restrict__ node_feat,
                 const int* __restrict__ srcv, const int* __restrict__ dstv,
                 const int* __restrict__ degs,
                 const float* __restrict__ W0, const float* __restrict__ b0,
                 const float* __restrict__ W1, const float* __restrict__ b1,
                 const float* __restrict__ W2, const float* __restrict__ b2,
                 const float* __restrict__ W3, const float* __restrict__ b3,
                 const float* __restrict__ cw1, const float* __restrict__ cb1,
                 const float* __restrict__ cw2, const float* __restrict__ cb2,
                 const float* __restrict__ ow,  const float* __restrict__ ob,
                 float* __restrict__ outp)
{
    __shared__ float Ybuf[NPG * 33];   // 33792 B; stride 33 -> bank (n+c)%32
    __shared__ int   srclist[EPG];     // 16384 B; in-edges grouped by dst; reused by tail
    __shared__ int   offs[NPG];
    __shared__ int   cnt [NPG];
    __shared__ int   degl[NPG];
    __shared__ float invd[NPG];
    __shared__ float keys[NPG];
    __shared__ int   wsum[4];
    // total ~55.3 KB

    const int g    = blockIdx.x;
    const int t    = threadIdx.x;
    const int n    = t & (NPG - 1);
    const int half = t >> 8;          // 0: channels 0..15, 1: channels 16..31
    const int co   = half * 16;

    // ================= degrees + wave-shuffle prefix scan (2 barriers) =======
    const int dn = degs[g * NPG + n];
    if (half == 0) {
        degl[n] = dn;
        cnt[n]  = 0;
        invd[n] = 1.0f / (float)(dn + 1);
    }
    {
        int v = (half == 0) ? dn : 0;
        const int lane = t & 63;
        #pragma unroll
        for (int off = 1; off < 64; off <<= 1) {
            int u = __shfl_up(v, off);
            if (lane >= off) v += u;
        }
        if (half == 0 && lane == 63) wsum[t >> 6] = v;   // wave totals (waves 0..3)
        __syncthreads();
        if (half == 0) {
            const int w = t >> 6;
            int base = 0;
            #pragma unroll
            for (int i = 0; i < 4; i++) base += (i < w) ? wsum[i] : 0;
            offs[n] = base + v - dn;   // exclusive prefix of in-degrees
        }
        __syncthreads();
    }

    // ================= edge-list build (counting sort by dst) ================
    {
        const int* sg = srcv + g * EPG;
        const int* dg = dstv + g * EPG;
        #pragma unroll
        for (int i = 0; i < EPG / 512; i++) {
            int e  = t + i * 512;
            int ss = sg[e] & (NPG - 1);   // graphs are 256-node aligned
            int dd = dg[e] & (NPG - 1);
            int p  = atomicAdd(&cnt[dd], 1);
            srclist[offs[dd] + p] = ss;
        }
    }

    // ================= phase 0: y0 = node_feat @ W0 ==========================
    // k-split: this thread covers k in [half*64, half*64+64). No local arrays
    // beyond acc[32] (constant-indexed, fully unrolled): float4s are by-value
    // named registers so SROA cannot fail (rule-#20 defense).
    {
        const float* nf  = node_feat + ((size_t)g * NPG + n) * FDIM + half * 64;
        const float4* nf4 = (const float4*)nf;
        const int kb = half * 64;

        float acc[32];
        #pragma unroll
        for (int c = 0; c < 32; c++) acc[c] = 0.f;

        auto fma4 = [&](float4 r, int kbase) {   // r by value: stays in VGPRs
            const float* w0 = W0 + (kbase + 0) * 32;
            const float* w1 = W0 + (kbase + 1) * 32;
            const float* w2 = W0 + (kbase + 2) * 32;
            const float* w3 = W0 + (kbase + 3) * 32;   // wave-uniform -> scalar
            #pragma unroll
            for (int c = 0; c < 32; c++) {
                float a = acc[c];
                a = fmaf(r.x, w0[c], a);
                a = fmaf(r.y, w1[c], a);
                a = fmaf(r.z, w2[c], a);
                a = fmaf(r.w, w3[c], a);
                acc[c] = a;
            }
        };

        float4 a0 = nf4[0],  a1 = nf4[1],  a2 = nf4[2],  a3 = nf4[3];
        float4 b0 = nf4[4],  b1 = nf4[5],  b2 = nf4[6],  b3 = nf4[7];
        fma4(a0, kb + 0);  fma4(a1, kb + 4);  fma4(a2, kb + 8);  fma4(a3, kb + 12);
        a0 = nf4[8];  a1 = nf4[9];  a2 = nf4[10]; a3 = nf4[11];
        fma4(b0, kb + 16); fma4(b1, kb + 20); fma4(b2, kb + 24); fma4(b3, kb + 28);
        b0 = nf4[12]; b1 = nf4[13]; b2 = nf4[14]; b3 = nf4[15];
        fma4(a0, kb + 32); fma4(a1, kb + 36); fma4(a2, kb + 40); fma4(a3, kb + 44);
        fma4(b0, kb + 48); fma4(b1, kb + 52); fma4(b2, kb + 56); fma4(b3, kb + 60);

        __syncthreads();   // edge build complete; Ybuf first use
        if (half == 0) {
            #pragma unroll
            for (int c = 0; c < 32; c++) Ybuf[n * 33 + c] = acc[c];
        }
        __syncthreads();
        if (half == 1) {
            #pragma unroll
            for (int c = 0; c < 32; c++) Ybuf[n * 33 + c] += acc[c];
        }
        __syncthreads();
    }

    const float iv = invd[n];
    const int   o  = offs[n];
    const int   d  = degl[n];

    // pooled (my 16-channel half) = y[n] + sum_{in-edges} y[src]
    auto agg16 = [&](float (&h)[16]) {
        const float* self = &Ybuf[n * 33 + co];
        #pragma unroll
        for (int c = 0; c < 16; c++) h[c] = self[c];
        for (int j = 0; j < d; j++) {
            const float* yr = &Ybuf[srclist[o + j] * 33 + co];
            #pragma unroll
            for (int c = 0; c < 16; c++) h[c] += yr[c];
        }
    };
    auto act16 = [&](float (&h)[16], const float* bb) {
        #pragma unroll
        for (int c = 0; c < 16; c++) h[c] = tanhf((h[c] + bb[co + c]) * iv);
    };
    // y_next = h @ Wn, k-split across the pair; combine via 2 barriered passes
    auto matml16 = [&](const float (&h)[16], const float* Wn) {
        float a[32];
        #pragma unroll
        for (int c = 0; c < 32; c++) a[c] = 0.f;
        #pragma unroll
        for (int kk = 0; kk < 16; kk++) {
            const float* wr = Wn + (co + kk) * 32;   // wave-uniform -> scalar loads
            const float  hk = h[kk];
            #pragma unroll
            for (int c = 0; c < 32; c++) a[c] = fmaf(hk, wr[c], a[c]);
        }
        __syncthreads();   // all agg reads of old Ybuf complete
        if (half == 0) {
            #pragma unroll
            for (int c = 0; c < 32; c++) Ybuf[n * 33 + c] = a[c];
        }
        __syncthreads();
        if (half == 1) {
            #pragma unroll
            for (int c = 0; c < 32; c++) Ybuf[n * 33 + c] += a[c];
        }
        __syncthreads();
    };

    // ================= 4 GNN layers =================
    float h1[16], h2[16], h3[16];
    agg16(h1); act16(h1, b0); matml16(h1, W1);
    agg16(h2); act16(h2, b1); matml16(h2, W2);
    agg16(h3); act16(h3, b2);
    {   // layer 3 projection: y3 = h3 @ W3 (32x1), k-split + combine
        float a3 = 0.f;
        #pragma unroll
        for (int kk = 0; kk < 16; kk++) a3 = fmaf(h3[kk], W3[co + kk], a3);
        __syncthreads();   // all layer-2 agg reads complete
        if (half == 0) Ybuf[n * 33] = a3;
        __syncthreads();
        if (half == 1) Ybuf[n * 33] += a3;
        __syncthreads();
    }
    float kv;
    {   // layer 3 aggregate (1-wide) + activation -> sort key (both halves redundant)
        float s = Ybuf[n * 33];
        for (int j = 0; j < d; j++) s += Ybuf[srclist[o + j] * 33];
        kv = tanhf((s + b3[0]) * iv);
        if (half == 0) keys[n] = kv;
    }
    __syncthreads();

    // ================= sortpool: rank-based top-K (jax tie-break: lower idx) ==
    int rank = 0;
    #pragma unroll 4
    for (int j = 0; j < NPG; j++) {
        float vj = keys[j];
        rank += ((vj > kv) || ((vj == kv) && (j < n))) ? 1 : 0;
    }

    // ================= export selected Z rows, then conv tail ================
    float* sp    = (float*)srclist;   // 2910 floats (srclist dead from here)
    float* x1    = sp + 30 * 97;      // 480
    float* xp    = x1 + 480;          // 240
    float* dense = xp + 240;          // 352  (total 3982 floats <= 4096)

    if (rank < KTOP) {
        float* dp = sp + rank * 97 + co;
        #pragma unroll
        for (int c = 0; c < 16; c++) dp[c]      = h1[c];
        #pragma unroll
        for (int c = 0; c < 16; c++) dp[32 + c] = h2[c];
        #pragma unroll
        for (int c = 0; c < 16; c++) dp[64 + c] = h3[c];
        if (half == 0) sp[rank * 97 + 96] = kv;
    }
    __syncthreads();

    // conv1: kernel width 97, stride 97 -> per-row dot; out [16][30], relu
    for (int idx = t; idx < 480; idx += 512) {
        int k = idx >> 4, c = idx & 15;
        float s = cb1[c];
        for (int dd = 0; dd < 97; dd++) s = fmaf(sp[k * 97 + dd], cw1[c * 97 + dd], s);
        x1[c * 30 + k] = fmaxf(s, 0.f);
    }
    __syncthreads();
    // maxpool1d(2,2) -> [16][15]
    for (int idx = t; idx < 240; idx += 512) {
        int c = idx / 15, k = idx - c * 15;
        xp[idx] = fmaxf(x1[c * 30 + 2 * k], x1[c * 30 + 2 * k + 1]);
    }
    __syncthreads();
    // conv2: [32][16][5] VALID over 15 -> [32][11], relu; dense idx = c*11+j
    for (int idx = t; idx < 352; idx += 512) {
        int c = idx / 11, j = idx - c * 11;
        float s = cb2[c];
        for (int i2 = 0; i2 < 16; i2++) {
            #pragma unroll
            for (int tt = 0; tt < 5; tt++)
                s = fmaf(xp[i2 * 15 + j + tt], cw2[(c * 16 + i2) * 5 + tt], s);
        }
        dense[idx] = fmaxf(s, 0.f);
    }
    __syncthreads();
    // output: relu(relu(dense @ out_w + out_b)) -> [2]
    if (t < 64) {
        float a0 = 0.f, a1 = 0.f;
        for (int dd = t; dd < 352; dd += 64) {
            float v = dense[dd];
            a0 = fmaf(v, ow[dd * 2],     a0);
            a1 = fmaf(v, ow[dd * 2 + 1], a1);
        }
        #pragma unroll
        for (int off2 = 32; off2 > 0; off2 >>= 1) {
            a0 += __shfl_down(a0, off2);
            a1 += __shfl_down(a1, off2);
        }
        if (t == 0) {
            outp[g * 2 + 0] = fmaxf(a0 + ob[0], 0.f);
            outp[g * 2 + 1] = fmaxf(a1 + ob[1], 0.f);
        }
    }
}

extern "C" void kernel_launch(void* const* d_in, const int* in_sizes, int n_in,
                              void* d_out, int out_size, void* d_ws, size_t ws_size,
                              hipStream_t stream) {
    const float* node_feat = (const float*)d_in[0];
    const int*   src       = (const int*)  d_in[1];
    const int*   dst       = (const int*)  d_in[2];
    const int*   degsp     = (const int*)  d_in[3];
    const float* W0 = (const float*)d_in[4];
    const float* b0 = (const float*)d_in[5];
    const float* W1 = (const float*)d_in[6];
    const float* b1 = (const float*)d_in[7];
    const float* W2 = (const float*)d_in[8];
    const float* b2 = (const float*)d_in[9];
    const float* W3 = (const float*)d_in[10];
    const float* b3 = (const float*)d_in[11];
    const float* cw1 = (const float*)d_in[12];
    const float* cb1 = (const float*)d_in[13];
    const float* cw2 = (const float*)d_in[14];
    const float* cb2 = (const float*)d_in[15];
    const float* ow  = (const float*)d_in[16];
    const float* ob  = (const float*)d_in[17];

    dgcnn_fused<<<dim3(256), dim3(512), 0, stream>>>(
        node_feat, src, dst, degsp,
        W0, b0, W1, b1, W2, b2, W3, b3,
        cw1, cb1, cw2, cb2, ow, ob, (float*)d_out);
}